// Round 1
// baseline (36.862 us; speedup 1.0000x reference)
//
#include <hip/hip_runtime.h>
#include <math.h>

// DCT-II 8x8 orthonormal matrix constants (match reference _dct_matrix in f32)
#define A0f 0.35355339059327373f
#define B1f 0.49039264020161522f
#define B3f 0.41573480615127262f
#define B5f 0.27778511650980114f
#define B7f 0.09754516100806412f
#define C2f 0.46193976625564337f
#define C6f 0.19134171618254489f

// y[k] = sum_n D[k][n] x[n]  (even/odd symmetry factorization, exact)
__device__ __forceinline__ void dct1d(const float x[8], float y[8]) {
    float s0 = x[0] + x[7], s1 = x[1] + x[6], s2 = x[2] + x[5], s3 = x[3] + x[4];
    float d0 = x[0] - x[7], d1 = x[1] - x[6], d2 = x[2] - x[5], d3 = x[3] - x[4];
    y[0] = A0f * ((s0 + s3) + (s1 + s2));
    y[4] = A0f * ((s0 + s3) - (s1 + s2));
    y[2] = C2f * s0 + C6f * s1 - C6f * s2 - C2f * s3;
    y[6] = C6f * s0 - C2f * s1 + C2f * s2 - C6f * s3;
    y[1] = B1f * d0 + B3f * d1 + B5f * d2 + B7f * d3;
    y[3] = B3f * d0 - B7f * d1 - B1f * d2 - B5f * d3;
    y[5] = B5f * d0 - B1f * d1 + B7f * d2 + B3f * d3;
    y[7] = B7f * d0 - B5f * d1 + B3f * d2 - B1f * d3;
}

// x[n] = sum_k D[k][n] y[k]
__device__ __forceinline__ void idct1d(const float y[8], float x[8]) {
    float ea = A0f * (y[0] + y[4]);
    float eb = A0f * (y[0] - y[4]);
    float p0 = C2f * y[2] + C6f * y[6];
    float p1 = C6f * y[2] - C2f * y[6];
    float e0 = ea + p0, e1 = eb + p1, e2 = eb - p1, e3 = ea - p0;
    float o0 = B1f * y[1] + B3f * y[3] + B5f * y[5] + B7f * y[7];
    float o1 = B3f * y[1] - B7f * y[3] - B1f * y[5] - B5f * y[7];
    float o2 = B5f * y[1] - B1f * y[3] + B7f * y[5] + B3f * y[7];
    float o3 = B7f * y[1] - B5f * y[3] + B3f * y[5] - B1f * y[7];
    x[0] = e0 + o0; x[7] = e0 - o0;
    x[1] = e1 + o1; x[6] = e1 - o1;
    x[2] = e2 + o2; x[5] = e2 - o2;
    x[3] = e3 + o3; x[4] = e3 - o3;
}

// One 64x16 pixel tile per 256-thread block.
// Tile contains 16 Y blocks (8x2) + 4 Cb + 4 Cr subsampled blocks = 24 8x8 blocks.
// Waves 0..2 process 8 blocks each (thread p = column p of its block); wave 3 idles in DCT phase.
__global__ __launch_bounds__(256) void jpeg_fused(
    const float* __restrict__ x, const float* __restrict__ ytab,
    const float* __restrict__ ctab, float* __restrict__ out)
{
    __shared__ float Yt[16][72];      // Y tile (y-128), stride 72 -> <=2-way banks
    __shared__ float Cst[2][8][40];   // subsampled Cb/Cr (no +128), stride 40
    __shared__ float Pc[2][16][33];   // horizontal chroma pair-sums
    __shared__ float Tr[24][72];      // per-block transpose scratch (8 rows x stride 9)

    const int tid = threadIdx.x;
    const int bid = blockIdx.x;
    const int b   = bid >> 10;        // 1024 tiles per image (64 rows x 16 cols)
    const int t_  = bid & 1023;
    const int trr = t_ >> 4;          // tile row 0..63
    const int tcc = t_ & 15;          // tile col 0..15
    const int y0  = trr << 4;
    const int x0  = tcc << 6;
    const int imgBase = b * 3145728;  // b*3*1024*1024

    // ---------------- staging: load RGB, color convert, store Y + chroma pair sums
    {
        const int row = tid >> 4;     // 0..15
        const int c4  = tid & 15;     // float4 index
        const int rowOff = (y0 + row) * 1024 + x0 + (c4 << 2);
        const float4 r4 = *(const float4*)(x + imgBase + rowOff);
        const float4 g4 = *(const float4*)(x + imgBase + 1048576 + rowOff);
        const float4 b4 = *(const float4*)(x + imgBase + 2097152 + rowOff);
        float ya[4], cba[4], cra[4];
        const float* rp = (const float*)&r4;
        const float* gp = (const float*)&g4;
        const float* bp = (const float*)&b4;
#pragma unroll
        for (int k = 0; k < 4; ++k) {
            float r = rp[k] * 255.0f;
            float g = gp[k] * 255.0f;
            float bl = bp[k] * 255.0f;
            ya[k]  = (0.299f * r + 0.587f * g + 0.114f * bl) - 128.0f;
            cba[k] = -0.168736f * r - 0.331264f * g + 0.5f * bl;       // cb - 128
            cra[k] = 0.5f * r - 0.418688f * g - 0.081312f * bl;        // cr - 128
        }
#pragma unroll
        for (int k = 0; k < 4; ++k) Yt[row][(c4 << 2) + k] = ya[k];
        Pc[0][row][(c4 << 1)]     = cba[0] + cba[1];
        Pc[0][row][(c4 << 1) + 1] = cba[2] + cba[3];
        Pc[1][row][(c4 << 1)]     = cra[0] + cra[1];
        Pc[1][row][(c4 << 1) + 1] = cra[2] + cra[3];
    }
    __syncthreads();

    // ---------------- chroma 2x2 subsample
    {
        const int i = tid >> 5;   // 0..7
        const int j = tid & 31;   // 0..31
        Cst[0][i][j] = 0.25f * (Pc[0][2 * i][j] + Pc[0][2 * i + 1][j]);
        Cst[1][i][j] = 0.25f * (Pc[1][2 * i][j] + Pc[1][2 * i + 1][j]);
    }
    __syncthreads();

    // ---------------- DCT -> quantize -> dequantize -> IDCT per 8x8 block
    {
        const int wv  = tid >> 6;
        const int sub = (tid >> 3) & 7;
        const int p   = tid & 7;
        const int blk = (wv << 3) + sub;   // 0..31; 24..31 idle (uniform per wave)
        if (blk < 24) {
            float* Xb; int stride; const float* tabp;
            if (blk < 16) {
                Xb = &Yt[(blk >> 3) << 3][(blk & 7) << 3]; stride = 72; tabp = ytab;
            } else if (blk < 20) {
                Xb = &Cst[0][0][(blk - 16) << 3]; stride = 40; tabp = ctab;
            } else {
                Xb = &Cst[1][0][(blk - 20) << 3]; stride = 40; tabp = ctab;
            }
            // quant table row p (rounded + clipped, matches reference)
            float qt[8];
#pragma unroll
            for (int k = 0; k < 8; ++k)
                qt[k] = fminf(fmaxf(rintf(tabp[(p << 3) + k]), 1.0f), 32767.0f);

            // load column p of block
            float v0[8];
#pragma unroll
            for (int i = 0; i < 8; ++i) v0[i] = Xb[i * stride + p];

            // vertical DCT (along rows index i)
            float t[8];
            dct1d(v0, t);

            // transpose 1: S[j*9+a] = t[a][j]  (thread p holds column p)
            float* S = &Tr[blk][0];
#pragma unroll
            for (int a = 0; a < 8; ++a) S[p * 9 + a] = t[a];
            float r1[8];
#pragma unroll
            for (int j = 0; j < 8; ++j) r1[j] = S[j * 9 + p];   // row p of t

            // horizontal DCT -> coef row p
            float cf[8];
            dct1d(r1, cf);

            // quantize + dequantize (rintf = round half to even, like jnp.round)
#pragma unroll
            for (int k = 0; k < 8; ++k) cf[k] = rintf(cf[k] / qt[k]) * qt[k];

            // horizontal IDCT -> row p of intermediate v
            float vrow[8];
            idct1d(cf, vrow);

            // transpose 2: S[p*9+j] = v[p][j]; read column p
#pragma unroll
            for (int j = 0; j < 8; ++j) S[p * 9 + j] = vrow[j];
            float vc[8];
#pragma unroll
            for (int a = 0; a < 8; ++a) vc[a] = S[a * 9 + p];

            // vertical IDCT -> reconstructed column p
            float rec[8];
            idct1d(vc, rec);
#pragma unroll
            for (int i = 0; i < 8; ++i) Xb[i * stride + p] = rec[i];
        }
    }
    __syncthreads();

    // ---------------- upsample chroma, YCbCr->RGB, store
    {
        const int row  = tid >> 4;
        const int c4   = tid & 15;
        const int srow = row >> 1;
        const float cb0 = Cst[0][srow][(c4 << 1)];
        const float cb1 = Cst[0][srow][(c4 << 1) + 1];
        const float cr0 = Cst[1][srow][(c4 << 1)];
        const float cr1 = Cst[1][srow][(c4 << 1) + 1];
        float4 R4, G4, B4;
        float* Rp = (float*)&R4; float* Gp = (float*)&G4; float* Bp = (float*)&B4;
#pragma unroll
        for (int k = 0; k < 4; ++k) {
            float Yv = Yt[row][(c4 << 2) + k] + 128.0f;
            float cb = (k < 2) ? cb0 : cb1;
            float cr = (k < 2) ? cr0 : cr1;
            float R = Yv + 1.402f * cr;
            float G = Yv - 0.344136f * cb - 0.714136f * cr;
            float Bl = Yv + 1.772f * cb;
            Rp[k] = R * (1.0f / 255.0f);
            Gp[k] = G * (1.0f / 255.0f);
            Bp[k] = Bl * (1.0f / 255.0f);
        }
        const int rowOff = (y0 + row) * 1024 + x0 + (c4 << 2);
        *(float4*)(out + imgBase + rowOff)           = R4;
        *(float4*)(out + imgBase + 1048576 + rowOff) = G4;
        *(float4*)(out + imgBase + 2097152 + rowOff) = B4;
    }
}

extern "C" void kernel_launch(void* const* d_in, const int* in_sizes, int n_in,
                              void* d_out, int out_size, void* d_ws, size_t ws_size,
                              hipStream_t stream) {
    const float* x    = (const float*)d_in[0];
    const float* ytab = (const float*)d_in[1];
    const float* ctab = (const float*)d_in[2];
    float* out = (float*)d_out;
    const int B = in_sizes[0] / 3145728;   // 3*1024*1024 per image
    const int grid = B * 1024;             // 64x16 tiles per image
    jpeg_fused<<<grid, 256, 0, stream>>>(x, ytab, ctab, out);
}